// Round 2
// baseline (701.619 us; speedup 1.0000x reference)
//
#include <hip/hip_runtime.h>

// PhysicsAttention fused kernel, MI355X (gfx950).
// Shapes: N=64, C=256, T=64, V=25, H=8, d=32.
// One workgroup per (n,t): full fusion QKV -> attention -> proj -> residual.
// bf16 MFMA (16x16x32) for all three matmuls; f32 softmax.

typedef short bf16x8 __attribute__((ext_vector_type(8)));
typedef short short4v __attribute__((ext_vector_type(4)));
typedef float f32x4 __attribute__((ext_vector_type(4)));

__device__ __forceinline__ unsigned short f2bf(float f) {
  union { float f; unsigned u; } v; v.f = f;
  unsigned r = v.u + 0x7fffu + ((v.u >> 16) & 1u);
  return (unsigned short)(r >> 16);
}
__device__ __forceinline__ float bf2f(unsigned short s) {
  union { unsigned u; float f; } v; v.u = ((unsigned)s) << 16;
  return v.f;
}

// ---- pre-kernel: convert Wqkv (768x256) and Wproj (256x256) to bf16 in ws ----
__global__ void convert_weights(const float* __restrict__ wqkv,
                                const float* __restrict__ wproj,
                                unsigned short* __restrict__ wout) {
  int i = blockIdx.x * blockDim.x + threadIdx.x;
  const int total = 768 * 256 + 256 * 256;
  for (; i < total; i += gridDim.x * blockDim.x) {
    float f = (i < 768 * 256) ? wqkv[i] : wproj[i - 768 * 256];
    wout[i] = f2bf(f);
  }
}

// XOR swizzle on element index (bf16 elems): flips elem bits 3..5 by row,
// i.e. byte bits 4..6 -> conflict-free-ish ds_read_b128 at 512B row stride.
#define SWZ(tok, e) ((e) ^ (((tok) & 7) << 3))

__global__ __launch_bounds__(256, 2)
void phys_attn_fused(const float* __restrict__ x,
                     const float* __restrict__ bqkv,
                     const float* __restrict__ bproj,
                     const float* __restrict__ hop_w,
                     const float* __restrict__ hop_grid,
                     const unsigned short* __restrict__ wbf,
                     float* __restrict__ out) {
  // LDS: 57,984 B total -> 2 blocks/CU
  __shared__ unsigned short x_tok[32 * 256];   // [tok][c] swizzled, bf16
  __shared__ unsigned short xatt[32 * 256];    // [tok][c] swizzled, bf16
  __shared__ unsigned short qk_t[32 * 136];    // [tok][o' 0..127], pitch 136
  __shared__ unsigned short val_s[64 * 48];    // [dd' 0..63][tok], pitch 48
  __shared__ unsigned short p_s[4 * 16 * 48];  // per-wave [vloc][u], pitch 48
  __shared__ float pen[32 * 33];               // hop penalty (+INF mask u>=25)

  const int tid = threadIdx.x;
  const int b = blockIdx.x;
  const int n = b >> 6, t = b & 63;
  const int w = tid >> 6;
  const int lane = tid & 63;
  const int l15 = lane & 15, lg = lane >> 4;

  const unsigned short* Wq = wbf;              // 768x256 bf16
  const unsigned short* Wp = wbf + 768 * 256;  // 256x256 bf16

  // ---- phase 0: stage x (transposed to token-major), penalty table ----
  {
    const float* xb = x + (size_t)n * 409600 + (size_t)t * 25;
    // zero ghost token rows 25..31 (so ghost qkv = bias, finite)
    for (int r = 25; r < 32; ++r) x_tok[SWZ(r, r * 256 + tid)] = 0;
    for (int i = tid; i < 6400; i += 256) {
      int c = i / 25;
      int v = i - c * 25;
      x_tok[SWZ(v, v * 256 + c)] = f2bf(xb[c * 1600 + v]);
    }
    float hw = hop_w[0];
    for (int i = tid; i < 1024; i += 256) {
      int v = i >> 5, u = i & 31;
      float pv = (u < 25) ? ((v < 25) ? hw * hop_grid[v * 25 + u] : 0.0f)
                          : __builtin_inff();
      pen[v * 33 + u] = pv;
    }
  }
  __syncthreads();

  const float scale = 0.17677669529663687f;  // 1/sqrt(32)

  for (int pr = 0; pr < 4; ++pr) {  // head pair: heads 2*pr, 2*pr+1
    // ---- QKV GEMM: 192 rows (q0,q1,k0,k1,v0,v1) x 32 toks, K=256 ----
    for (int j = 0; j < 6; ++j) {
      int tIdx = w * 6 + j;          // 24 tiles over 4 waves
      int mt = tIdx >> 1, nt = tIdx & 1;
      int g = mt >> 1, sub = mt & 1;
      int hpar = g & 1;              // which head of the pair
      int sec = g >> 1;              // 0:q 1:k 2:val
      int wrow0 = sec * 256 + (pr * 2 + hpar) * 32 + sub * 16;
      int tok = nt * 16 + l15;
      f32x4 acc = {0.f, 0.f, 0.f, 0.f};
      int arow = (wrow0 + l15) * 256 + lg * 8;
      int brow = tok * 256 + lg * 8;
      for (int ks = 0; ks < 8; ++ks) {
        bf16x8 a = *(const bf16x8*)(Wq + arow + ks * 32);
        bf16x8 bfr = *(const bf16x8*)(x_tok + SWZ(tok, brow + ks * 32));
        acc = __builtin_amdgcn_mfma_f32_16x16x32_bf16(a, bfr, acc, 0, 0, 0);
      }
      int rb = wrow0 + lg * 4;  // D rows = wrow0 + lg*4 + r, col = tok
      unsigned short h0 = f2bf(acc[0] + bqkv[rb + 0]);
      unsigned short h1 = f2bf(acc[1] + bqkv[rb + 1]);
      unsigned short h2 = f2bf(acc[2] + bqkv[rb + 2]);
      unsigned short h3 = f2bf(acc[3] + bqkv[rb + 3]);
      if (sec < 2) {
        // q,k transposed: qk_t[tok][o'], o' = sec*64 + hpar*32 + d
        int op = sec * 64 + hpar * 32 + sub * 16 + lg * 4;
        short4v pk = {(short)h0, (short)h1, (short)h2, (short)h3};
        *(short4v*)(qk_t + tok * 136 + op) = pk;
      } else {
        // val d-major: val_s[dd'][tok], dd' = hpar*32 + d
        int dd = hpar * 32 + sub * 16 + lg * 4;
        val_s[(dd + 0) * 48 + tok] = h0;
        val_s[(dd + 1) * 48 + tok] = h1;
        val_s[(dd + 2) * 48 + tok] = h2;
        val_s[(dd + 3) * 48 + tok] = h3;
      }
    }
    __syncthreads();

    // ---- attention: wave -> (head hsel, v-halftile mtq) ----
    {
      int hsel = w >> 1;
      int mtq = w & 1;
      int vbase = mtq * 16;
      int hglob = pr * 2 + hsel;
      // A-frag q: A[v][d], d contiguous in qk_t row
      bf16x8 aq = *(const bf16x8*)(qk_t + (vbase + l15) * 136 + hsel * 32 + lg * 8);
      f32x4 att0, att1;
      {
        f32x4 z = {0.f, 0.f, 0.f, 0.f};
        bf16x8 bk0 = *(const bf16x8*)(qk_t + (0 + l15) * 136 + 64 + hsel * 32 + lg * 8);
        att0 = __builtin_amdgcn_mfma_f32_16x16x32_bf16(aq, bk0, z, 0, 0, 0);
        bf16x8 bk1 = *(const bf16x8*)(qk_t + (16 + l15) * 136 + 64 + hsel * 32 + lg * 8);
        att1 = __builtin_amdgcn_mfma_f32_16x16x32_bf16(aq, bk1, z, 0, 0, 0);
      }
      int pbase = w * 768;
      for (int r = 0; r < 4; ++r) {
        int v = vbase + lg * 4 + r;
        float f0 = att0[r] * scale - pen[v * 33 + l15];
        float f1 = att1[r] * scale - pen[v * 33 + 16 + l15];
        float m = fmaxf(f0, f1);
        m = fmaxf(m, __shfl_xor(m, 1));
        m = fmaxf(m, __shfl_xor(m, 2));
        m = fmaxf(m, __shfl_xor(m, 4));
        m = fmaxf(m, __shfl_xor(m, 8));
        float e0 = __expf(f0 - m);
        float e1 = __expf(f1 - m);
        float s = e0 + e1;
        s += __shfl_xor(s, 1);
        s += __shfl_xor(s, 2);
        s += __shfl_xor(s, 4);
        s += __shfl_xor(s, 8);
        float inv = 1.0f / s;
        p_s[pbase + (lg * 4 + r) * 48 + l15] = f2bf(e0 * inv);
        p_s[pbase + (lg * 4 + r) * 48 + 16 + l15] = f2bf(e1 * inv);
      }
      // PV: D[dd][vloc] = sum_u val[dd][u] * p[vloc][u]
      bf16x8 bp = *(const bf16x8*)(p_s + pbase + l15 * 48 + lg * 8);
      for (int mt2 = 0; mt2 < 2; ++mt2) {
        bf16x8 av = *(const bf16x8*)(val_s + (hsel * 32 + mt2 * 16 + l15) * 48 + lg * 8);
        f32x4 z = {0.f, 0.f, 0.f, 0.f};
        f32x4 o = __builtin_amdgcn_mfma_f32_16x16x32_bf16(av, bp, z, 0, 0, 0);
        int c0 = hglob * 32 + mt2 * 16 + lg * 4;
        int tok = vbase + l15;
        short4v pk = {(short)f2bf(o[0]), (short)f2bf(o[1]),
                      (short)f2bf(o[2]), (short)f2bf(o[3])};
        *(short4v*)(xatt + SWZ(tok, tok * 256 + c0)) = pk;
      }
    }
    __syncthreads();
  }

  // ---- output projection + bias + residual ----
  for (int j = 0; j < 8; ++j) {
    int tIdx = w * 8 + j;             // 32 tiles over 4 waves
    int mt = tIdx >> 1, nt = tIdx & 1;
    int tok = nt * 16 + l15;
    f32x4 acc = {0.f, 0.f, 0.f, 0.f};
    int arow = (mt * 16 + l15) * 256 + lg * 8;
    int brow = tok * 256 + lg * 8;
    for (int ks = 0; ks < 8; ++ks) {
      bf16x8 a = *(const bf16x8*)(Wp + arow + ks * 32);
      bf16x8 bfr = *(const bf16x8*)(xatt + SWZ(tok, brow + ks * 32));
      acc = __builtin_amdgcn_mfma_f32_16x16x32_bf16(a, bfr, acc, 0, 0, 0);
    }
    if (tok < 25) {
      int o0 = mt * 16 + lg * 4;
      short4v xr = *(const short4v*)(x_tok + SWZ(tok, tok * 256 + o0));
      float* op = out + (size_t)n * 409600 + (size_t)t * 25 + tok;
      op[(size_t)(o0 + 0) * 1600] = acc[0] + bproj[o0 + 0] + bf2f((unsigned short)xr[0]);
      op[(size_t)(o0 + 1) * 1600] = acc[1] + bproj[o0 + 1] + bf2f((unsigned short)xr[1]);
      op[(size_t)(o0 + 2) * 1600] = acc[2] + bproj[o0 + 2] + bf2f((unsigned short)xr[2]);
      op[(size_t)(o0 + 3) * 1600] = acc[3] + bproj[o0 + 3] + bf2f((unsigned short)xr[3]);
    }
  }
}

extern "C" void kernel_launch(void* const* d_in, const int* in_sizes, int n_in,
                              void* d_out, int out_size, void* d_ws, size_t ws_size,
                              hipStream_t stream) {
  const float* x        = (const float*)d_in[0];
  const float* wqkv     = (const float*)d_in[1];
  const float* bqkv     = (const float*)d_in[2];
  const float* wproj    = (const float*)d_in[3];
  const float* bproj    = (const float*)d_in[4];
  const float* hop_w    = (const float*)d_in[5];
  const float* hop_grid = (const float*)d_in[6];
  float* out = (float*)d_out;
  unsigned short* wbf = (unsigned short*)d_ws;  // 524,288 B used

  convert_weights<<<dim3(256), dim3(256), 0, stream>>>(wqkv, wproj, wbf);
  phys_attn_fused<<<dim3(64 * 64), dim3(256), 0, stream>>>(
      x, bqkv, bproj, hop_w, hop_grid, wbf, out);
}

// Round 3
// 617.900 us; speedup vs baseline: 1.1355x; 1.1355x over previous
//
#include <hip/hip_runtime.h>

// PhysicsAttention fused kernel, MI355X (gfx950).
// Shapes: N=64, C=256, T=64, V=25, H=8, d=32.
// One workgroup (512 thr, 8 waves) per (n,t); 4 heads per QKV/attn phase.
// bf16 MFMA (16x16x32) for all three matmuls; f32 softmax.

typedef short bf16x8 __attribute__((ext_vector_type(8)));
typedef short short4v __attribute__((ext_vector_type(4)));
typedef float f32x4 __attribute__((ext_vector_type(4)));

__device__ __forceinline__ unsigned short f2bf(float f) {
  union { float f; unsigned u; } v; v.f = f;
  unsigned r = v.u + 0x7fffu + ((v.u >> 16) & 1u);
  return (unsigned short)(r >> 16);
}
__device__ __forceinline__ float bf2f(unsigned short s) {
  union { unsigned u; float f; } v; v.u = ((unsigned)s) << 16;
  return v.f;
}

// ---- pre-kernel: convert Wqkv (768x256) and Wproj (256x256) to bf16 in ws ----
__global__ void convert_weights(const float* __restrict__ wqkv,
                                const float* __restrict__ wproj,
                                unsigned short* __restrict__ wout) {
  int i = blockIdx.x * blockDim.x + threadIdx.x;
  const int total = 768 * 256 + 256 * 256;
  for (; i < total; i += gridDim.x * blockDim.x) {
    float f = (i < 768 * 256) ? wqkv[i] : wproj[i - 768 * 256];
    wout[i] = f2bf(f);
  }
}

// XOR swizzle on element index (bf16 elems): flips elem bits 3..5 by row ->
// conflict-free-ish ds_read_b128 at 512B row stride. Preserves 8-elem align.
#define SWZ(tok, e) ((e) ^ (((tok) & 7) << 3))

__global__ __launch_bounds__(512, 4)
void phys_attn_fused(const float* __restrict__ x,
                     const float* __restrict__ bqkv,
                     const float* __restrict__ bproj,
                     const float* __restrict__ hop_w,
                     const float* __restrict__ hop_grid,
                     const unsigned short* __restrict__ wbf,
                     float* __restrict__ out) {
  // LDS total: 16384+16384+16896+10240+10240+4224 = 74,368 B -> 2 blocks/CU
  __shared__ unsigned short x_tok[32 * 256];   // [tok][c] swizzled, bf16
  __shared__ unsigned short xatt[32 * 256];    // [tok][c] swizzled, bf16
  __shared__ unsigned short qk_t[32 * 264];    // [tok][q:0..127 | k:128..255], pitch 264
  __shared__ unsigned short val_s[128 * 40];   // [hh*32+d][tok], pitch 40
  __shared__ unsigned short p_s[8 * 16 * 40];  // per-wave [vloc][u], pitch 40
  __shared__ float pen[32 * 33];               // hop penalty (+INF mask u>=25)

  const int tid = threadIdx.x;
  const int b = blockIdx.x;
  const int n = b >> 6, t = b & 63;
  const int w = tid >> 6;
  const int lane = tid & 63;
  const int l15 = lane & 15, lg = lane >> 4;

  const unsigned short* Wq = wbf;              // 768x256 bf16
  const unsigned short* Wp = wbf + 768 * 256;  // 256x256 bf16

  // ---- phase 0: stage x (transposed to token-major), penalty table ----
  {
    const float* xb = x + (size_t)n * 409600 + (size_t)t * 25;
    // zero ghost token rows 25..31 (so ghost qkv = bias, finite)
    for (int idx = tid; idx < 1792; idx += 512) {
      int r = 25 + (idx >> 8), c = idx & 255;
      x_tok[SWZ(r, r * 256 + c)] = 0;
    }
#pragma unroll 4
    for (int i = tid; i < 6400; i += 512) {
      int c = i / 25;
      int v = i - c * 25;
      x_tok[SWZ(v, v * 256 + c)] = f2bf(xb[c * 1600 + v]);
    }
    float hw = hop_w[0];
    for (int i = tid; i < 1024; i += 512) {
      int v = i >> 5, u = i & 31;
      float pv = (u < 25) ? ((v < 25) ? hw * hop_grid[v * 25 + u] : 0.0f)
                          : __builtin_inff();
      pen[v * 33 + u] = pv;
    }
  }
  __syncthreads();

  const float scale = 0.17677669529663687f;  // 1/sqrt(32)

  for (int g = 0; g < 2; ++g) {  // head group: heads 4g .. 4g+3
    // ---- QKV GEMM: 384 rows (q x4h, k x4h, v x4h) x 32 toks, K=256 ----
#pragma unroll
    for (int j = 0; j < 6; ++j) {
      int tIdx = w * 6 + j;          // 48 tiles over 8 waves
      int mt = tIdx >> 1, nt = tIdx & 1;
      int sec = mt >> 3;             // 0:q 1:k 2:val
      int rem = mt & 7;
      int hh = rem >> 1;             // head within group (0..3)
      int sub = rem & 1;
      int wrow0 = sec * 256 + (g * 4 + hh) * 32 + sub * 16;
      int tok = nt * 16 + l15;
      f32x4 acc = {0.f, 0.f, 0.f, 0.f};
      int arow = (wrow0 + l15) * 256 + lg * 8;
      int brow = tok * 256 + lg * 8;
#pragma unroll
      for (int ks = 0; ks < 8; ++ks) {
        bf16x8 a = *(const bf16x8*)(Wq + arow + ks * 32);
        bf16x8 bfr = *(const bf16x8*)(x_tok + SWZ(tok, brow + ks * 32));
        acc = __builtin_amdgcn_mfma_f32_16x16x32_bf16(a, bfr, acc, 0, 0, 0);
      }
      int rb = wrow0 + lg * 4;  // D rows = wrow0 + lg*4 + r, col = tok
      unsigned short h0 = f2bf(acc[0] + bqkv[rb + 0]);
      unsigned short h1 = f2bf(acc[1] + bqkv[rb + 1]);
      unsigned short h2 = f2bf(acc[2] + bqkv[rb + 2]);
      unsigned short h3 = f2bf(acc[3] + bqkv[rb + 3]);
      if (sec < 2) {
        // q,k transposed: qk_t[tok][col], col = sec*128 + hh*32 + d
        int op = sec * 128 + hh * 32 + sub * 16 + lg * 4;
        short4v pk = {(short)h0, (short)h1, (short)h2, (short)h3};
        *(short4v*)(qk_t + tok * 264 + op) = pk;
      } else {
        // val d-major: val_s[dd][tok], dd = hh*32 + d
        int dd = hh * 32 + sub * 16 + lg * 4;
        val_s[(dd + 0) * 40 + tok] = h0;
        val_s[(dd + 1) * 40 + tok] = h1;
        val_s[(dd + 2) * 40 + tok] = h2;
        val_s[(dd + 3) * 40 + tok] = h3;
      }
    }
    __syncthreads();

    // ---- attention: wave -> (head hh, v-halftile) ----
    {
      int hh = w >> 1;
      int vbase = (w & 1) * 16;
      int hglob = g * 4 + hh;
      // A-frag q: A[v][d], d contiguous in qk_t row
      bf16x8 aq = *(const bf16x8*)(qk_t + (vbase + l15) * 264 + hh * 32 + lg * 8);
      f32x4 att0, att1;
      {
        f32x4 z = {0.f, 0.f, 0.f, 0.f};
        bf16x8 bk0 = *(const bf16x8*)(qk_t + (0 + l15) * 264 + 128 + hh * 32 + lg * 8);
        att0 = __builtin_amdgcn_mfma_f32_16x16x32_bf16(aq, bk0, z, 0, 0, 0);
        bf16x8 bk1 = *(const bf16x8*)(qk_t + (16 + l15) * 264 + 128 + hh * 32 + lg * 8);
        att1 = __builtin_amdgcn_mfma_f32_16x16x32_bf16(aq, bk1, z, 0, 0, 0);
      }
      int pbase = w * 640;
#pragma unroll
      for (int r = 0; r < 4; ++r) {
        int v = vbase + lg * 4 + r;
        float f0 = att0[r] * scale - pen[v * 33 + l15];
        float f1 = att1[r] * scale - pen[v * 33 + 16 + l15];
        float m = fmaxf(f0, f1);
        m = fmaxf(m, __shfl_xor(m, 1));
        m = fmaxf(m, __shfl_xor(m, 2));
        m = fmaxf(m, __shfl_xor(m, 4));
        m = fmaxf(m, __shfl_xor(m, 8));
        float e0 = __expf(f0 - m);
        float e1 = __expf(f1 - m);
        float s = e0 + e1;
        s += __shfl_xor(s, 1);
        s += __shfl_xor(s, 2);
        s += __shfl_xor(s, 4);
        s += __shfl_xor(s, 8);
        float inv = 1.0f / s;
        p_s[pbase + (lg * 4 + r) * 40 + l15] = f2bf(e0 * inv);
        p_s[pbase + (lg * 4 + r) * 40 + 16 + l15] = f2bf(e1 * inv);
      }
      // PV: D[dd][vloc] = sum_u val[dd][u] * p[vloc][u]
      bf16x8 bp = *(const bf16x8*)(p_s + pbase + l15 * 40 + lg * 8);
#pragma unroll
      for (int mt2 = 0; mt2 < 2; ++mt2) {
        bf16x8 av = *(const bf16x8*)(val_s + (hh * 32 + mt2 * 16 + l15) * 40 + lg * 8);
        f32x4 z = {0.f, 0.f, 0.f, 0.f};
        f32x4 o = __builtin_amdgcn_mfma_f32_16x16x32_bf16(av, bp, z, 0, 0, 0);
        int c0 = hglob * 32 + mt2 * 16 + lg * 4;
        int tok = vbase + l15;
        short4v pk = {(short)f2bf(o[0]), (short)f2bf(o[1]),
                      (short)f2bf(o[2]), (short)f2bf(o[3])};
        *(short4v*)(xatt + SWZ(tok, tok * 256 + c0)) = pk;
      }
    }
    __syncthreads();
  }

  // ---- output projection + bias + residual ----
#pragma unroll
  for (int j = 0; j < 4; ++j) {
    int tIdx = w * 4 + j;             // 32 tiles over 8 waves
    int mt = tIdx >> 1, nt = tIdx & 1;
    int tok = nt * 16 + l15;
    f32x4 acc = {0.f, 0.f, 0.f, 0.f};
    int arow = (mt * 16 + l15) * 256 + lg * 8;
    int brow = tok * 256 + lg * 8;
#pragma unroll
    for (int ks = 0; ks < 8; ++ks) {
      bf16x8 a = *(const bf16x8*)(Wp + arow + ks * 32);
      bf16x8 bfr = *(const bf16x8*)(xatt + SWZ(tok, brow + ks * 32));
      acc = __builtin_amdgcn_mfma_f32_16x16x32_bf16(a, bfr, acc, 0, 0, 0);
    }
    if (tok < 25) {
      int o0 = mt * 16 + lg * 4;
      short4v xr = *(const short4v*)(x_tok + SWZ(tok, tok * 256 + o0));
      float* op = out + (size_t)n * 409600 + (size_t)t * 25 + tok;
      op[(size_t)(o0 + 0) * 1600] = acc[0] + bproj[o0 + 0] + bf2f((unsigned short)xr[0]);
      op[(size_t)(o0 + 1) * 1600] = acc[1] + bproj[o0 + 1] + bf2f((unsigned short)xr[1]);
      op[(size_t)(o0 + 2) * 1600] = acc[2] + bproj[o0 + 2] + bf2f((unsigned short)xr[2]);
      op[(size_t)(o0 + 3) * 1600] = acc[3] + bproj[o0 + 3] + bf2f((unsigned short)xr[3]);
    }
  }
}

extern "C" void kernel_launch(void* const* d_in, const int* in_sizes, int n_in,
                              void* d_out, int out_size, void* d_ws, size_t ws_size,
                              hipStream_t stream) {
  const float* x        = (const float*)d_in[0];
  const float* wqkv     = (const float*)d_in[1];
  const float* bqkv     = (const float*)d_in[2];
  const float* wproj    = (const float*)d_in[3];
  const float* bproj    = (const float*)d_in[4];
  const float* hop_w    = (const float*)d_in[5];
  const float* hop_grid = (const float*)d_in[6];
  float* out = (float*)d_out;
  unsigned short* wbf = (unsigned short*)d_ws;  // 524,288 B used

  convert_weights<<<dim3(256), dim3(256), 0, stream>>>(wqkv, wproj, wbf);
  phys_attn_fused<<<dim3(64 * 64), dim3(512), 0, stream>>>(
      x, bqkv, bproj, hop_w, hop_grid, wbf, out);
}